// Round 4
// baseline (146.211 us; speedup 1.0000x reference)
//
#include <hip/hip_runtime.h>

// RgbNet: hash-grid encode + MLP 120->64->64->64->3, split into two kernels.
//
// Kernel A (encode): thread = (ray, pair); 2048 blocks x 256 thr (~30 waves/CU, no LDS,
//   no barriers) -> maximal memory-level parallelism for the scattered level-3..5 gathers.
//   Writes feat4[pair][ray] (float4, coalesced) into d_ws.
// Kernel B (MLP): 64 rays/block, 1024 thr = 16 waves, grid 256.
//   Activations in LDS rows [ray][k] padded to stride 124/68 floats -> ds_read_b128,
//   bank-group conflict-free ((31r+p)%8, (17r)%8 hit all groups; 2-way is free).
//   Weights via per-lane global loads (VMEM/vmcnt path, runtime-uniform -> L1 broadcast)
//   so DS(lgkm) and weights(vmcnt) pipeline on independent counters (no lgkmcnt(0) drains
//   from SMEM/DS mixing). LDS: sFeat 64x124 + sHa 64x68, sHb aliases sFeat -> 48 KB.

#define NSAMP 300
#define HSIZE (1u << 19)

__global__ __launch_bounds__(256, 6) void encode_kernel(
    const float4* __restrict__ x,       // [N] rows: sx,sy,ex,ey
    const int*    __restrict__ idxf,    // [N]
    const float4* __restrict__ emb,     // [6 * 2^19] float4 entries
    float4*       __restrict__ feat,    // [30][N] float4
    int N)
{
    const int tid = threadIdx.x;
    const int r   = tid & 63;
    const int p   = blockIdx.y * 4 + (tid >> 6);   // pair id 0..31 (30 used)
    const int ray = blockIdx.x * 64 + r;
    if (p >= 30) return;

    const float4 xr = x[ray];
    const int    i0 = idxf[ray];
    const int d = p / 6;                 // gather offset index 0..4 (d-2 in ref)
    const int l = p - d * 6;             // level 0..5
    int s = i0 + d - 2;
    s = max(0, min(s, NSAMP - 1));
    const float t   = (float)s * (1.0f / 299.0f);
    const float omt = 1.0f - t;
    const int   R   = 4 << l;
    const float fR  = (float)R;
    const float px = (xr.x * omt + xr.z * t) * fR;
    const float py = (xr.y * omt + xr.w * t) * fR;
    const float pz = t * fR;
    const float fx0 = floorf(px), fy0 = floorf(py), fz0 = floorf(pz);
    const float wx = px - fx0, wy = py - fy0, wz = pz - fz0;
    const int ix = (int)fx0, iy = (int)fy0, iz = (int)fz0;
    const int Rp1 = R + 1;
    const float4* __restrict__ ebase = emb + (size_t)l * HSIZE;

    float ax = 0.f, ay = 0.f, az = 0.f, aw = 0.f;
    #pragma unroll
    for (int c = 0; c < 8; ++c) {
        const int ox = (c >> 2) & 1, oy = (c >> 1) & 1, oz = c & 1;
        int cx = min(ix + ox, R); cx = max(cx, 0);
        int cy = min(iy + oy, R); cy = max(cy, 0);
        int cz = min(iz + oz, R); cz = max(cz, 0);
        unsigned idx;
        if (l < 5) {
            idx = (unsigned)(cx + cy * Rp1 + cz * Rp1 * Rp1);   // dense level
        } else {
            idx = ((unsigned)cx * 1u
                 ^ (unsigned)cy * 2654435761u
                 ^ (unsigned)cz * 805459861u) & (HSIZE - 1u);   // hashed level
        }
        const float4 e = ebase[idx];
        const float cw = (ox ? wx : 1.f - wx)
                       * (oy ? wy : 1.f - wy)
                       * (oz ? wz : 1.f - wz);
        ax = fmaf(cw, e.x, ax);
        ay = fmaf(cw, e.y, ay);
        az = fmaf(cw, e.z, az);
        aw = fmaf(cw, e.w, aw);
    }
    feat[(size_t)p * N + ray] = make_float4(ax, ay, az, aw);
}

__global__ __launch_bounds__(1024, 4) void mlp_kernel(
    const float4* __restrict__ feat,    // [30][N] float4
    const float* __restrict__ W1, const float* __restrict__ b1,
    const float* __restrict__ W2, const float* __restrict__ b2,
    const float* __restrict__ W3, const float* __restrict__ b3,
    const float* __restrict__ W4, const float* __restrict__ b4,
    float* __restrict__ out, int N)
{
    __shared__ float sm[12288];          // 48 KB
    float* sFeat = sm;                   // [64][124]  (31744 B)
    float* sHa   = sm + 7936;            // [64][68]   (17408 B)
    float* sHb   = sm;                   // [64][68]   aliases sFeat (dead after L1)

    const int tid = threadIdx.x;
    const int r   = tid & 63;            // local ray (= lane)
    const int w   = tid >> 6;            // wave id 0..15 (kept divergent -> VMEM weights)
    const int ray = blockIdx.x * 64 + r;

    // ---- stage feat -> LDS rows [ray][k], k = p*4+c (matches ref concat order) ----
    {
        const float4 v = feat[(size_t)w * N + ray];
        *(float4*)&sFeat[r * 124 + w * 4] = v;
        if (w < 14) {
            const float4 v2 = feat[(size_t)(w + 16) * N + ray];
            *(float4*)&sFeat[r * 124 + (w + 16) * 4] = v2;
        }
    }
    __syncthreads();

    const int j0 = w * 4;                // wave owns neurons j0..j0+3
    float hh[4];

    // ---------------- Layer 1: 120 -> 64 ----------------
    #pragma unroll
    for (int jj = 0; jj < 4; ++jj) hh[jj] = b1[j0 + jj];
    #pragma unroll 2
    for (int kc = 0; kc < 120; kc += 4) {
        const float4 f = *(const float4*)&sFeat[r * 124 + kc];
        #pragma unroll
        for (int jj = 0; jj < 4; ++jj) {
            const float4 wv = *(const float4*)&W1[(j0 + jj) * 120 + kc];
            hh[jj] = fmaf(f.x, wv.x, hh[jj]);
            hh[jj] = fmaf(f.y, wv.y, hh[jj]);
            hh[jj] = fmaf(f.z, wv.z, hh[jj]);
            hh[jj] = fmaf(f.w, wv.w, hh[jj]);
        }
    }
    {
        float4 o;
        o.x = fmaxf(hh[0], 0.f); o.y = fmaxf(hh[1], 0.f);
        o.z = fmaxf(hh[2], 0.f); o.w = fmaxf(hh[3], 0.f);
        *(float4*)&sHa[r * 68 + j0] = o;
    }
    __syncthreads();

    // ---------------- Layer 2: 64 -> 64 ----------------
    #pragma unroll
    for (int jj = 0; jj < 4; ++jj) hh[jj] = b2[j0 + jj];
    #pragma unroll 2
    for (int kc = 0; kc < 64; kc += 4) {
        const float4 f = *(const float4*)&sHa[r * 68 + kc];
        #pragma unroll
        for (int jj = 0; jj < 4; ++jj) {
            const float4 wv = *(const float4*)&W2[(j0 + jj) * 64 + kc];
            hh[jj] = fmaf(f.x, wv.x, hh[jj]);
            hh[jj] = fmaf(f.y, wv.y, hh[jj]);
            hh[jj] = fmaf(f.z, wv.z, hh[jj]);
            hh[jj] = fmaf(f.w, wv.w, hh[jj]);
        }
    }
    __syncthreads();                     // sFeat dead; safe to write sHb(=sFeat)
    {
        float4 o;
        o.x = fmaxf(hh[0], 0.f); o.y = fmaxf(hh[1], 0.f);
        o.z = fmaxf(hh[2], 0.f); o.w = fmaxf(hh[3], 0.f);
        *(float4*)&sHb[r * 68 + j0] = o;
    }
    __syncthreads();

    // ---------------- Layer 3: 64 -> 64 ----------------
    #pragma unroll
    for (int jj = 0; jj < 4; ++jj) hh[jj] = b3[j0 + jj];
    #pragma unroll 2
    for (int kc = 0; kc < 64; kc += 4) {
        const float4 f = *(const float4*)&sHb[r * 68 + kc];
        #pragma unroll
        for (int jj = 0; jj < 4; ++jj) {
            const float4 wv = *(const float4*)&W3[(j0 + jj) * 64 + kc];
            hh[jj] = fmaf(f.x, wv.x, hh[jj]);
            hh[jj] = fmaf(f.y, wv.y, hh[jj]);
            hh[jj] = fmaf(f.z, wv.z, hh[jj]);
            hh[jj] = fmaf(f.w, wv.w, hh[jj]);
        }
    }
    __syncthreads();                     // all waves done reading sHa from L2 phase
    {
        float4 o;
        o.x = fmaxf(hh[0], 0.f); o.y = fmaxf(hh[1], 0.f);
        o.z = fmaxf(hh[2], 0.f); o.w = fmaxf(hh[3], 0.f);
        *(float4*)&sHa[r * 68 + j0] = o;
    }
    __syncthreads();

    // ---------------- Output: 64 -> 3 ----------------
    if (w < 3) {
        float acc = b4[w];
        #pragma unroll 2
        for (int kc = 0; kc < 64; kc += 4) {
            const float4 f  = *(const float4*)&sHa[r * 68 + kc];
            const float4 wv = *(const float4*)&W4[w * 64 + kc];
            acc = fmaf(f.x, wv.x, acc);
            acc = fmaf(f.y, wv.y, acc);
            acc = fmaf(f.z, wv.z, acc);
            acc = fmaf(f.w, wv.w, acc);
        }
        out[(size_t)ray * 3 + w] = acc;
    }
}

extern "C" void kernel_launch(void* const* d_in, const int* in_sizes, int n_in,
                              void* d_out, int out_size, void* d_ws, size_t ws_size,
                              hipStream_t stream) {
    const float4* x    = (const float4*)d_in[0];
    const int*    idxf = (const int*)   d_in[1];
    const float4* emb  = (const float4*)d_in[2];
    const float*  W1   = (const float*) d_in[3];
    const float*  b1   = (const float*) d_in[4];
    const float*  W2   = (const float*) d_in[5];
    const float*  b2   = (const float*) d_in[6];
    const float*  W3   = (const float*) d_in[7];
    const float*  b3   = (const float*) d_in[8];
    const float*  W4   = (const float*) d_in[9];
    const float*  b4   = (const float*) d_in[10];
    float* out = (float*)d_out;

    const int N = in_sizes[0] / 4;              // 16384 rays (x is [N,4])
    float4* feat = (float4*)d_ws;               // [30][N] float4 = 7.86 MB

    const int rayblocks = (N + 63) / 64;        // 256
    hipLaunchKernelGGL(encode_kernel, dim3(rayblocks, 8), dim3(256), 0, stream,
                       x, idxf, emb, feat, N);
    hipLaunchKernelGGL(mlp_kernel, dim3(rayblocks), dim3(1024), 0, stream,
                       feat, W1, b1, W2, b2, W3, b3, W4, b4, out, N);
}

// Round 5
// 140.801 us; speedup vs baseline: 1.0384x; 1.0384x over previous
//
#include <hip/hip_runtime.h>

// RgbNet: fused hash-grid encode (5 samples/ray, 6 levels) + MLP 120->64->64->64->3.
// R4 lesson: kernel split regressed (launch + round-trip); R2/R3 lesson: instruction-mix
// tweaks neutral -> the limiter is barrier-exposed latency with ONE block/CU.
// This round: 32 rays/block, 512 thr = 8 waves, grid = 512, __launch_bounds__(512,6)
//   -> VGPR <= ~85 -> 6 waves/SIMD -> 3 co-resident blocks/CU (24 waves/CU). While one
//   block sits at __syncthreads (gather latency tail), two others issue FMAs/gathers.
// Lane map: r = lane&31 (ray), half = lane>>5; unit u = 2w+half.
//   Phase 0: unit u gathers pairs {u, u+16} for its 32 rays -> sFeat[k][r] (bank r, 2-way free).
//   Phase 1-3: wave w, half h owns neurons [8w+4h, +4); activations k-major in LDS
//   (same-address broadcast across halves); weights per-lane VMEM float4 (L1 broadcast,
//   vmcnt pipe independent of DS/lgkm). sHb aliases sFeat -> 23.5 KB LDS total.

#define NSAMP 300
#define HSIZE (1u << 19)
#define RAYS 32

__global__ __launch_bounds__(512, 6) void rgbnet_fused(
    const float4* __restrict__ x,       // [N] rows: sx,sy,ex,ey
    const int*    __restrict__ idxf,    // [N]
    const float4* __restrict__ emb,     // [6 * 2^19] float4 entries
    const float* __restrict__ W1, const float* __restrict__ b1,
    const float* __restrict__ W2, const float* __restrict__ b2,
    const float* __restrict__ W3, const float* __restrict__ b3,
    const float* __restrict__ W4, const float* __restrict__ b4,
    float* __restrict__ out, int N)
{
    __shared__ float sm[120 * RAYS + 64 * RAYS];   // 23552 B
    float* sFeat = sm;                  // [120][32]
    float* sHa   = sm + 120 * RAYS;     // [64][32]
    float* sHb   = sm;                  // [64][32], aliases sFeat (dead after Layer 1)

    const int tid  = threadIdx.x;
    const int lane = tid & 63;
    const int r    = lane & 31;         // local ray
    const int half = lane >> 5;         // 0/1 within wave
    const int w    = tid >> 6;          // wave id 0..7
    const int u    = w * 2 + half;      // unit id 0..15
    const int ray  = blockIdx.x * RAYS + r;

    // ---------------- Phase 0: grid encoding ----------------
    {
        const float4 xr = x[ray];
        const int    i0 = idxf[ray];

        for (int p = u; p < 30; p += 16) {     // unit's pairs: {u, u+16}
            const int d = p / 6;               // gather offset index 0..4 (d-2 in ref)
            const int l = p - d * 6;           // level 0..5
            int s = i0 + d - 2;
            s = max(0, min(s, NSAMP - 1));
            const float t   = (float)s * (1.0f / 299.0f);
            const float omt = 1.0f - t;
            const int   R   = 4 << l;
            const float fR  = (float)R;
            const float px = (xr.x * omt + xr.z * t) * fR;
            const float py = (xr.y * omt + xr.w * t) * fR;
            const float pz = t * fR;
            const float fx0 = floorf(px), fy0 = floorf(py), fz0 = floorf(pz);
            const float wx = px - fx0, wy = py - fy0, wz = pz - fz0;
            const int ix = (int)fx0, iy = (int)fy0, iz = (int)fz0;
            const int Rp1 = R + 1;
            const float4* __restrict__ ebase = emb + (size_t)l * HSIZE;

            float ax = 0.f, ay = 0.f, az = 0.f, aw = 0.f;
            #pragma unroll
            for (int c = 0; c < 8; ++c) {
                const int ox = (c >> 2) & 1, oy = (c >> 1) & 1, oz = c & 1;
                int cx = min(ix + ox, R); cx = max(cx, 0);
                int cy = min(iy + oy, R); cy = max(cy, 0);
                int cz = min(iz + oz, R); cz = max(cz, 0);
                unsigned idx;
                if (l < 5) {
                    idx = (unsigned)(cx + cy * Rp1 + cz * Rp1 * Rp1);   // dense level
                } else {
                    idx = ((unsigned)cx * 1u
                         ^ (unsigned)cy * 2654435761u
                         ^ (unsigned)cz * 805459861u) & (HSIZE - 1u);   // hashed level
                }
                const float4 e = ebase[idx];
                const float cw = (ox ? wx : 1.f - wx)
                               * (oy ? wy : 1.f - wy)
                               * (oz ? wz : 1.f - wz);
                ax = fmaf(cw, e.x, ax);
                ay = fmaf(cw, e.y, ay);
                az = fmaf(cw, e.z, az);
                aw = fmaf(cw, e.w, aw);
            }
            const int k0 = p * 4;              // = d*24 + l*4, matches ref concat order
            sFeat[(k0 + 0) * RAYS + r] = ax;
            sFeat[(k0 + 1) * RAYS + r] = ay;
            sFeat[(k0 + 2) * RAYS + r] = az;
            sFeat[(k0 + 3) * RAYS + r] = aw;
        }
    }
    __syncthreads();

    const int j0 = w * 8 + half * 4;           // this half-wave's 4 neurons
    float hh[4];

    // ---------------- Layer 1: 120 -> 64 ----------------
    {
        const float4 bv = *(const float4*)&b1[j0];
        hh[0] = bv.x; hh[1] = bv.y; hh[2] = bv.z; hh[3] = bv.w;
    }
    #pragma unroll 2
    for (int kc = 0; kc < 120; kc += 4) {
        const float f0 = sFeat[(kc + 0) * RAYS + r];
        const float f1 = sFeat[(kc + 1) * RAYS + r];
        const float f2 = sFeat[(kc + 2) * RAYS + r];
        const float f3 = sFeat[(kc + 3) * RAYS + r];
        #pragma unroll
        for (int jj = 0; jj < 4; ++jj) {
            const float4 wv = *(const float4*)&W1[(j0 + jj) * 120 + kc];
            hh[jj] = fmaf(f0, wv.x, hh[jj]);
            hh[jj] = fmaf(f1, wv.y, hh[jj]);
            hh[jj] = fmaf(f2, wv.z, hh[jj]);
            hh[jj] = fmaf(f3, wv.w, hh[jj]);
        }
    }
    #pragma unroll
    for (int jj = 0; jj < 4; ++jj)
        sHa[(j0 + jj) * RAYS + r] = fmaxf(hh[jj], 0.f);
    __syncthreads();

    // ---------------- Layer 2: 64 -> 64 ----------------
    {
        const float4 bv = *(const float4*)&b2[j0];
        hh[0] = bv.x; hh[1] = bv.y; hh[2] = bv.z; hh[3] = bv.w;
    }
    #pragma unroll 2
    for (int kc = 0; kc < 64; kc += 4) {
        const float f0 = sHa[(kc + 0) * RAYS + r];
        const float f1 = sHa[(kc + 1) * RAYS + r];
        const float f2 = sHa[(kc + 2) * RAYS + r];
        const float f3 = sHa[(kc + 3) * RAYS + r];
        #pragma unroll
        for (int jj = 0; jj < 4; ++jj) {
            const float4 wv = *(const float4*)&W2[(j0 + jj) * 64 + kc];
            hh[jj] = fmaf(f0, wv.x, hh[jj]);
            hh[jj] = fmaf(f1, wv.y, hh[jj]);
            hh[jj] = fmaf(f2, wv.z, hh[jj]);
            hh[jj] = fmaf(f3, wv.w, hh[jj]);
        }
    }
    // sFeat is dead (all waves past barrier 1) -> safe to write sHb(=sFeat space) now.
    #pragma unroll
    for (int jj = 0; jj < 4; ++jj)
        sHb[(j0 + jj) * RAYS + r] = fmaxf(hh[jj], 0.f);
    __syncthreads();

    // ---------------- Layer 3: 64 -> 64 ----------------
    {
        const float4 bv = *(const float4*)&b3[j0];
        hh[0] = bv.x; hh[1] = bv.y; hh[2] = bv.z; hh[3] = bv.w;
    }
    #pragma unroll 2
    for (int kc = 0; kc < 64; kc += 4) {
        const float f0 = sHb[(kc + 0) * RAYS + r];
        const float f1 = sHb[(kc + 1) * RAYS + r];
        const float f2 = sHb[(kc + 2) * RAYS + r];
        const float f3 = sHb[(kc + 3) * RAYS + r];
        #pragma unroll
        for (int jj = 0; jj < 4; ++jj) {
            const float4 wv = *(const float4*)&W3[(j0 + jj) * 64 + kc];
            hh[jj] = fmaf(f0, wv.x, hh[jj]);
            hh[jj] = fmaf(f1, wv.y, hh[jj]);
            hh[jj] = fmaf(f2, wv.z, hh[jj]);
            hh[jj] = fmaf(f3, wv.w, hh[jj]);
        }
    }
    #pragma unroll
    for (int jj = 0; jj < 4; ++jj)
        sHa[(j0 + jj) * RAYS + r] = fmaxf(hh[jj], 0.f);
    __syncthreads();

    // ---------------- Output: 64 -> 3 (units 0..2 -> channels) ----------------
    if (u < 3) {
        float acc = b4[u];
        #pragma unroll 2
        for (int kc = 0; kc < 64; kc += 4) {
            const float f0 = sHa[(kc + 0) * RAYS + r];
            const float f1 = sHa[(kc + 1) * RAYS + r];
            const float f2 = sHa[(kc + 2) * RAYS + r];
            const float f3 = sHa[(kc + 3) * RAYS + r];
            const float4 wv = *(const float4*)&W4[u * 64 + kc];
            acc = fmaf(f0, wv.x, acc);
            acc = fmaf(f1, wv.y, acc);
            acc = fmaf(f2, wv.z, acc);
            acc = fmaf(f3, wv.w, acc);
        }
        out[(size_t)ray * 3 + u] = acc;
    }
}

extern "C" void kernel_launch(void* const* d_in, const int* in_sizes, int n_in,
                              void* d_out, int out_size, void* d_ws, size_t ws_size,
                              hipStream_t stream) {
    const float4* x    = (const float4*)d_in[0];
    const int*    idxf = (const int*)   d_in[1];
    const float4* emb  = (const float4*)d_in[2];
    const float*  W1   = (const float*) d_in[3];
    const float*  b1   = (const float*) d_in[4];
    const float*  W2   = (const float*) d_in[5];
    const float*  b2   = (const float*) d_in[6];
    const float*  W3   = (const float*) d_in[7];
    const float*  b3   = (const float*) d_in[8];
    const float*  W4   = (const float*) d_in[9];
    const float*  b4   = (const float*) d_in[10];
    float* out = (float*)d_out;

    const int N = in_sizes[0] / 4;              // 16384 rays (x is [N,4])
    const int blocks = (N + RAYS - 1) / RAYS;   // 512 blocks of 512 threads
    hipLaunchKernelGGL(rgbnet_fused, dim3(blocks), dim3(512), 0, stream,
                       x, idxf, emb, W1, b1, W2, b2, W3, b3, W4, b4, out, N);
}